// Round 1
// baseline (214.501 us; speedup 1.0000x reference)
//
#include <hip/hip_runtime.h>
#include <hip/hip_bf16.h>
#include <math.h>

// Fused self-attention for B=8, S=2048, D=64 (fp32 in/out), also materializing
// the full attention filter [B,S,S].
//
// Structure: one workgroup = 4 waves = 64 query rows of one batch.
//   Pass 1: stream K blocks (64 keys) through LDS, QK^T via 16x16x32 bf16 MFMA,
//           online softmax stats (m, l) per query row.
//   Pass 2: re-stream K (+V transposed) blocks, recompute scores, write the
//           normalized P tile to global (coalesced float4 via an LDS bounce that
//           also performs the MFMA C-layout -> A-layout transform), accumulate
//           O += P*V with MFMA.
// HBM floor: 134 MB filter write + 4 MB context + 12.6 MB reads ~= 24 us.

typedef short bf16x8 __attribute__((ext_vector_type(8)));
typedef short bf16x4 __attribute__((ext_vector_type(4)));
typedef float f32x4 __attribute__((ext_vector_type(4)));

#define BATCH 8
#define SDIM 2048
#define DDIM 64
#define KBLK 64
#define NBLK (SDIM / KBLK)   // 32
#define SCALE 0.125f         // 1/sqrt(64)

__device__ __forceinline__ short f2bf(float f) {
    unsigned x = __float_as_uint(f);
    x = (x + 0x7fffu + ((x >> 16) & 1u)) >> 16;   // RNE to bf16
    return (short)x;
}

__device__ __forceinline__ float fidx(const float4& v, int i) {
    return ((const float*)&v)[i];
}

__global__ __launch_bounds__(256, 1)
void attn_fused(const float* __restrict__ Kg, const float* __restrict__ Qg,
                const float* __restrict__ Vg, const int* __restrict__ Mg,
                float* __restrict__ Ctx, float* __restrict__ Filt)
{
    __shared__ short Klds[KBLK][72];     // [key][d] bf16, pad 72 (bank-spread, keeps 16B align)
    __shared__ short VTlds[DDIM][72];    // [d][key] bf16 (transposed for PV B-frags)
    __shared__ float Plds[4][16][68];    // per-wave P tile [qrow][key] fp32, pad 68
    __shared__ int   Mlds[KBLK];

    const int wg = blockIdx.x;
    const int b = wg & 7;                // batch -> XCD affinity (wg%8 dispatch)
    const int qtile = wg >> 3;           // 0..31, 64 queries each
    const int tid = threadIdx.x;
    const int w = tid >> 6;              // wave 0..3
    const int lane = tid & 63;
    const int col = lane & 15;           // MFMA n / m-lane index
    const int quad = lane >> 4;          // MFMA k-group / row-group

    const float* Kb = Kg + (size_t)b * SDIM * DDIM;
    const float* Qb = Qg + (size_t)b * SDIM * DDIM;
    const float* Vb = Vg + (size_t)b * SDIM * DDIM;
    const int*   Mb = Mg + (size_t)b * SDIM;
    float* Ctxb  = Ctx  + (size_t)b * SDIM * DDIM;
    float* Filtb = Filt + (size_t)b * SDIM * SDIM;

    const int qrow = qtile * 64 + w * 16 + col;   // A-frag row m = lane&15

    // ---- persistent Q fragments: A[m=col][k=quad*8+j], two 32-wide K chunks ----
    bf16x8 aq[2];
    {
        const float* qsrc = Qb + (size_t)qrow * DDIM + quad * 8;
        #pragma unroll
        for (int c = 0; c < 2; ++c) {
            float4 f0 = *(const float4*)(qsrc + c * 32);
            float4 f1 = *(const float4*)(qsrc + c * 32 + 4);
            bf16x8 a;
            a[0]=f2bf(f0.x); a[1]=f2bf(f0.y); a[2]=f2bf(f0.z); a[3]=f2bf(f0.w);
            a[4]=f2bf(f1.x); a[5]=f2bf(f1.y); a[6]=f2bf(f1.z); a[7]=f2bf(f1.w);
            aq[c] = a;
        }
    }

    // staging maps: K: thread -> (key, 16 d's); V: thread -> (4 keys, 4 d's) transposed
    const int sk_key = tid >> 2;
    const int sk_d0  = (tid & 3) * 16;
    const int sv_d0  = (tid & 15) * 4;
    const int sv_k0  = (tid >> 4) * 4;

    float m_run[4], l_run[4];
    #pragma unroll
    for (int r = 0; r < 4; ++r) { m_run[r] = -1e30f; l_run[r] = 0.0f; }

    // ========================== PASS 1: softmax stats ==========================
    float4 kreg[4];
    int mreg = 0;
    {
        const float* src = Kb + (size_t)sk_key * DDIM + sk_d0;
        #pragma unroll
        for (int i = 0; i < 4; ++i) kreg[i] = *(const float4*)(src + i * 4);
        if (tid < KBLK) mreg = Mb[tid];
    }

    for (int kb = 0; kb < NBLK; ++kb) {
        __syncthreads();
        {
            bf16x8 p0, p1;
            p0[0]=f2bf(kreg[0].x); p0[1]=f2bf(kreg[0].y); p0[2]=f2bf(kreg[0].z); p0[3]=f2bf(kreg[0].w);
            p0[4]=f2bf(kreg[1].x); p0[5]=f2bf(kreg[1].y); p0[6]=f2bf(kreg[1].z); p0[7]=f2bf(kreg[1].w);
            p1[0]=f2bf(kreg[2].x); p1[1]=f2bf(kreg[2].y); p1[2]=f2bf(kreg[2].z); p1[3]=f2bf(kreg[2].w);
            p1[4]=f2bf(kreg[3].x); p1[5]=f2bf(kreg[3].y); p1[6]=f2bf(kreg[3].z); p1[7]=f2bf(kreg[3].w);
            *(bf16x8*)&Klds[sk_key][sk_d0]     = p0;
            *(bf16x8*)&Klds[sk_key][sk_d0 + 8] = p1;
            if (tid < KBLK) Mlds[tid] = mreg;
        }
        __syncthreads();
        if (kb + 1 < NBLK) {   // register prefetch of next block (hides global latency)
            const float* src = Kb + (size_t)((kb + 1) * KBLK + sk_key) * DDIM + sk_d0;
            #pragma unroll
            for (int i = 0; i < 4; ++i) kreg[i] = *(const float4*)(src + i * 4);
            if (tid < KBLK) mreg = Mb[(kb + 1) * KBLK + tid];
        }

        float s[4][4];
        #pragma unroll
        for (int t = 0; t < 4; ++t) {
            f32x4 acc = {0.f, 0.f, 0.f, 0.f};
            #pragma unroll
            for (int c = 0; c < 2; ++c) {
                bf16x8 bk = *(const bf16x8*)&Klds[t * 16 + col][c * 32 + quad * 8];
                acc = __builtin_amdgcn_mfma_f32_16x16x32_bf16(aq[c], bk, acc, 0, 0, 0);
            }
            const int mk = Mlds[t * 16 + col];
            #pragma unroll
            for (int r = 0; r < 4; ++r)
                s[t][r] = mk ? -INFINITY : acc[r] * SCALE;   // mask==1 -> -inf (per reference)
        }
        // online (m,l) update; row r lives in the 16 lanes of this quad
        #pragma unroll
        for (int r = 0; r < 4; ++r) {
            float mx = fmaxf(fmaxf(s[0][r], s[1][r]), fmaxf(s[2][r], s[3][r]));
            mx = fmaxf(mx, __shfl_xor(mx, 1));
            mx = fmaxf(mx, __shfl_xor(mx, 2));
            mx = fmaxf(mx, __shfl_xor(mx, 4));
            mx = fmaxf(mx, __shfl_xor(mx, 8));
            const float mn = fmaxf(m_run[r], mx);
            float sum = __expf(s[0][r] - mn) + __expf(s[1][r] - mn)
                      + __expf(s[2][r] - mn) + __expf(s[3][r] - mn);
            sum += __shfl_xor(sum, 1);
            sum += __shfl_xor(sum, 2);
            sum += __shfl_xor(sum, 4);
            sum += __shfl_xor(sum, 8);
            l_run[r] = l_run[r] * __expf(m_run[r] - mn) + sum;
            m_run[r] = mn;
        }
    }

    float inv_l[4];
    #pragma unroll
    for (int r = 0; r < 4; ++r) inv_l[r] = 1.0f / l_run[r];

    // ==================== PASS 2: write P, accumulate O = P*V ====================
    f32x4 Oacc[4];
    #pragma unroll
    for (int dt = 0; dt < 4; ++dt) Oacc[dt] = (f32x4){0.f, 0.f, 0.f, 0.f};

    float4 vreg[4];
    {
        const float* srck = Kb + (size_t)sk_key * DDIM + sk_d0;
        #pragma unroll
        for (int i = 0; i < 4; ++i) kreg[i] = *(const float4*)(srck + i * 4);
        const float* srcv = Vb + (size_t)sv_k0 * DDIM + sv_d0;
        #pragma unroll
        for (int i = 0; i < 4; ++i) vreg[i] = *(const float4*)(srcv + (size_t)i * DDIM);
        if (tid < KBLK) mreg = Mb[tid];
    }

    for (int kb = 0; kb < NBLK; ++kb) {
        __syncthreads();
        {
            bf16x8 p0, p1;
            p0[0]=f2bf(kreg[0].x); p0[1]=f2bf(kreg[0].y); p0[2]=f2bf(kreg[0].z); p0[3]=f2bf(kreg[0].w);
            p0[4]=f2bf(kreg[1].x); p0[5]=f2bf(kreg[1].y); p0[6]=f2bf(kreg[1].z); p0[7]=f2bf(kreg[1].w);
            p1[0]=f2bf(kreg[2].x); p1[1]=f2bf(kreg[2].y); p1[2]=f2bf(kreg[2].z); p1[3]=f2bf(kreg[2].w);
            p1[4]=f2bf(kreg[3].x); p1[5]=f2bf(kreg[3].y); p1[6]=f2bf(kreg[3].z); p1[7]=f2bf(kreg[3].w);
            *(bf16x8*)&Klds[sk_key][sk_d0]     = p0;
            *(bf16x8*)&Klds[sk_key][sk_d0 + 8] = p1;
            #pragma unroll
            for (int dd = 0; dd < 4; ++dd) {   // 4x4 in-register transpose of V
                bf16x4 pv;
                pv[0] = f2bf(fidx(vreg[0], dd));
                pv[1] = f2bf(fidx(vreg[1], dd));
                pv[2] = f2bf(fidx(vreg[2], dd));
                pv[3] = f2bf(fidx(vreg[3], dd));
                *(bf16x4*)&VTlds[sv_d0 + dd][sv_k0] = pv;
            }
            if (tid < KBLK) Mlds[tid] = mreg;
        }
        __syncthreads();
        if (kb + 1 < NBLK) {
            const float* srck = Kb + (size_t)((kb + 1) * KBLK + sk_key) * DDIM + sk_d0;
            #pragma unroll
            for (int i = 0; i < 4; ++i) kreg[i] = *(const float4*)(srck + i * 4);
            const float* srcv = Vb + (size_t)((kb + 1) * KBLK + sv_k0) * DDIM + sv_d0;
            #pragma unroll
            for (int i = 0; i < 4; ++i) vreg[i] = *(const float4*)(srcv + (size_t)i * DDIM);
            if (tid < KBLK) mreg = Mb[(kb + 1) * KBLK + tid];
        }

        // recompute scores, normalize, park P tile in LDS (layout transform)
        #pragma unroll
        for (int t = 0; t < 4; ++t) {
            f32x4 acc = {0.f, 0.f, 0.f, 0.f};
            #pragma unroll
            for (int c = 0; c < 2; ++c) {
                bf16x8 bk = *(const bf16x8*)&Klds[t * 16 + col][c * 32 + quad * 8];
                acc = __builtin_amdgcn_mfma_f32_16x16x32_bf16(aq[c], bk, acc, 0, 0, 0);
            }
            const int mk = Mlds[t * 16 + col];
            #pragma unroll
            for (int r = 0; r < 4; ++r) {
                float p = mk ? 0.0f : __expf(acc[r] * SCALE - m_run[r]) * inv_l[r];
                Plds[w][quad * 4 + r][t * 16 + col] = p;   // C-layout scatter
            }
        }

        // coalesced global write of P: 16 rows x 64 keys, float4 per lane
        #pragma unroll
        for (int i = 0; i < 4; ++i) {
            const int row = i * 4 + quad;
            float4 pv = *(const float4*)&Plds[w][row][col * 4];
            *(float4*)(Filtb + (size_t)(qtile * 64 + w * 16 + row) * SDIM + kb * KBLK + col * 4) = pv;
        }

        // O += P * V  (A-frag from Plds, B-frag from VTlds)
        #pragma unroll
        for (int c = 0; c < 2; ++c) {
            float4 pa0 = *(const float4*)&Plds[w][col][c * 32 + quad * 8];
            float4 pa1 = *(const float4*)&Plds[w][col][c * 32 + quad * 8 + 4];
            bf16x8 ap;
            ap[0]=f2bf(pa0.x); ap[1]=f2bf(pa0.y); ap[2]=f2bf(pa0.z); ap[3]=f2bf(pa0.w);
            ap[4]=f2bf(pa1.x); ap[5]=f2bf(pa1.y); ap[6]=f2bf(pa1.z); ap[7]=f2bf(pa1.w);
            #pragma unroll
            for (int dt = 0; dt < 4; ++dt) {
                bf16x8 bv = *(const bf16x8*)&VTlds[dt * 16 + col][c * 32 + quad * 8];
                Oacc[dt] = __builtin_amdgcn_mfma_f32_16x16x32_bf16(ap, bv, Oacc[dt], 0, 0, 0);
            }
        }
    }

    // context write: C-layout (row = quad*4+r, d = dt*16+col)
    #pragma unroll
    for (int dt = 0; dt < 4; ++dt) {
        #pragma unroll
        for (int r = 0; r < 4; ++r) {
            Ctxb[(size_t)(qtile * 64 + w * 16 + quad * 4 + r) * DDIM + dt * 16 + col] = Oacc[dt][r];
        }
    }
}

extern "C" void kernel_launch(void* const* d_in, const int* in_sizes, int n_in,
                              void* d_out, int out_size, void* d_ws, size_t ws_size,
                              hipStream_t stream) {
    // setup_inputs order: key, query, value, query_attention_mask
    const float* Kg = (const float*)d_in[0];
    const float* Qg = (const float*)d_in[1];
    const float* Vg = (const float*)d_in[2];
    const int*   Mg = (const int*)d_in[3];
    float* Ctx  = (float*)d_out;                                   // [8,2048,64]
    float* Filt = (float*)d_out + (size_t)BATCH * SDIM * DDIM;     // [8,2048,2048]

    dim3 grid(BATCH * (SDIM / 64));   // 256 workgroups: b = wg&7 (XCD affinity), qtile = wg>>3
    dim3 block(256);
    attn_fused<<<grid, block, 0, stream>>>(Kg, Qg, Vg, Mg, Ctx, Filt);
}

// Round 3
// 202.730 us; speedup vs baseline: 1.0581x; 1.0581x over previous
//
#include <hip/hip_runtime.h>
#include <hip/hip_bf16.h>
#include <math.h>

// Fused self-attention, B=8, S=2048, D=64 fp32; outputs context [8,2048,64] and
// full attention filter [8,2048,2048].
//
// Round-3: identical to round-2 structure, with the attn_stats grid bug fixed
// (256 -> 1024 WGs; sp = wg>>8 decode requires 1024). Key-dim 4-way split:
//   K1 attn_stats: 1024 WGs, partial (m,l) per q-row over 512 keys -> ws
//   K2 attn_merge: merge 4 partials -> (m, 1/l); zero context region
//   K3 attn_emit : 1024 WGs, write filter tile direct-from-register (coalesced),
//                  PV via bf16 P tile in LDS, partial O via unsafeAtomicAdd
// LDS strides = 66 shorts (33 words, odd) to spread banks.

typedef short bf16x8 __attribute__((ext_vector_type(8)));
typedef short bf16x4 __attribute__((ext_vector_type(4)));
typedef float f32x4 __attribute__((ext_vector_type(4)));

#define BATCH 8
#define SDIM 2048
#define DDIM 64
#define KBLK 64
#define NBLK (SDIM / KBLK)      // 32
#define KSPLIT 4
#define BPW (NBLK / KSPLIT)     // 8 key-blocks per WG
#define NROWS (BATCH * SDIM)    // 16384
#define SCALE 0.125f
#define KSTR 66                 // LDS row stride in shorts (33 words, odd)

__device__ __forceinline__ short f2bf(float f) {
    unsigned x = __float_as_uint(f);
    x = (x + 0x7fffu + ((x >> 16) & 1u)) >> 16;   // RNE
    return (short)x;
}
__device__ __forceinline__ float fidx(const float4& v, int i) {
    return ((const float*)&v)[i];
}

// ============================ K1: partial softmax stats ============================
__global__ __launch_bounds__(256, 4)
void attn_stats(const float* __restrict__ Kg, const float* __restrict__ Qg,
                const int* __restrict__ Mg, float2* __restrict__ part)
{
    __shared__ short Klds[KBLK][KSTR];
    __shared__ int   Mlds[KBLK];

    const int wg = blockIdx.x;
    const int b = wg & 7;
    const int qt = (wg >> 3) & 31;
    const int sp = wg >> 8;
    const int tid = threadIdx.x;
    const int w = tid >> 6, lane = tid & 63, col = lane & 15, quad = lane >> 4;

    const float* Kb = Kg + (size_t)b * SDIM * DDIM;
    const float* Qb = Qg + (size_t)b * SDIM * DDIM;
    const int*   Mb = Mg + (size_t)b * SDIM;

    // Q A-fragments (persistent)
    bf16x8 aq[2];
    {
        const float* qsrc = Qb + (size_t)(qt * 64 + w * 16 + col) * DDIM + quad * 8;
        #pragma unroll
        for (int c = 0; c < 2; ++c) {
            float4 f0 = *(const float4*)(qsrc + c * 32);
            float4 f1 = *(const float4*)(qsrc + c * 32 + 4);
            bf16x8 a;
            a[0]=f2bf(f0.x); a[1]=f2bf(f0.y); a[2]=f2bf(f0.z); a[3]=f2bf(f0.w);
            a[4]=f2bf(f1.x); a[5]=f2bf(f1.y); a[6]=f2bf(f1.z); a[7]=f2bf(f1.w);
            aq[c] = a;
        }
    }

    const int sk_key = tid >> 2;
    const int sk_d0  = (tid & 3) * 16;
    const int kb0 = sp * BPW * KBLK;      // first key of this split

    float m_run[4], l_run[4];
    #pragma unroll
    for (int r = 0; r < 4; ++r) { m_run[r] = -1e30f; l_run[r] = 0.0f; }

    float4 kreg[4];
    int mreg = 0;
    {
        const float* src = Kb + (size_t)(kb0 + sk_key) * DDIM + sk_d0;
        #pragma unroll
        for (int i = 0; i < 4; ++i) kreg[i] = *(const float4*)(src + i * 4);
        if (tid < KBLK) mreg = Mb[kb0 + tid];
    }

    for (int kb = 0; kb < BPW; ++kb) {
        __syncthreads();
        {
            bf16x8 p0, p1;
            p0[0]=f2bf(kreg[0].x); p0[1]=f2bf(kreg[0].y); p0[2]=f2bf(kreg[0].z); p0[3]=f2bf(kreg[0].w);
            p0[4]=f2bf(kreg[1].x); p0[5]=f2bf(kreg[1].y); p0[6]=f2bf(kreg[1].z); p0[7]=f2bf(kreg[1].w);
            p1[0]=f2bf(kreg[2].x); p1[1]=f2bf(kreg[2].y); p1[2]=f2bf(kreg[2].z); p1[3]=f2bf(kreg[2].w);
            p1[4]=f2bf(kreg[3].x); p1[5]=f2bf(kreg[3].y); p1[6]=f2bf(kreg[3].z); p1[7]=f2bf(kreg[3].w);
            *(bf16x8*)&Klds[sk_key][sk_d0]     = p0;
            *(bf16x8*)&Klds[sk_key][sk_d0 + 8] = p1;
            if (tid < KBLK) Mlds[tid] = mreg;
        }
        __syncthreads();
        if (kb + 1 < BPW) {
            const float* src = Kb + (size_t)(kb0 + (kb + 1) * KBLK + sk_key) * DDIM + sk_d0;
            #pragma unroll
            for (int i = 0; i < 4; ++i) kreg[i] = *(const float4*)(src + i * 4);
            if (tid < KBLK) mreg = Mb[kb0 + (kb + 1) * KBLK + tid];
        }

        float s[4][4];
        #pragma unroll
        for (int t = 0; t < 4; ++t) {
            f32x4 acc = {0.f, 0.f, 0.f, 0.f};
            #pragma unroll
            for (int c = 0; c < 2; ++c) {
                bf16x8 bk = *(const bf16x8*)&Klds[t * 16 + col][c * 32 + quad * 8];
                acc = __builtin_amdgcn_mfma_f32_16x16x32_bf16(aq[c], bk, acc, 0, 0, 0);
            }
            const int mk = Mlds[t * 16 + col];
            #pragma unroll
            for (int r = 0; r < 4; ++r)
                s[t][r] = mk ? -INFINITY : acc[r] * SCALE;
        }
        #pragma unroll
        for (int r = 0; r < 4; ++r) {
            float mx = fmaxf(fmaxf(s[0][r], s[1][r]), fmaxf(s[2][r], s[3][r]));
            mx = fmaxf(mx, __shfl_xor(mx, 1));
            mx = fmaxf(mx, __shfl_xor(mx, 2));
            mx = fmaxf(mx, __shfl_xor(mx, 4));
            mx = fmaxf(mx, __shfl_xor(mx, 8));
            const float mn = fmaxf(m_run[r], mx);
            float sum = __expf(s[0][r] - mn) + __expf(s[1][r] - mn)
                      + __expf(s[2][r] - mn) + __expf(s[3][r] - mn);
            sum += __shfl_xor(sum, 1);
            sum += __shfl_xor(sum, 2);
            sum += __shfl_xor(sum, 4);
            sum += __shfl_xor(sum, 8);
            l_run[r] = l_run[r] * __expf(m_run[r] - mn) + sum;
            m_run[r] = mn;
        }
    }

    if (col == 0) {
        #pragma unroll
        for (int r = 0; r < 4; ++r)
            part[(size_t)sp * NROWS + b * SDIM + qt * 64 + w * 16 + quad * 4 + r] =
                make_float2(m_run[r], l_run[r]);
    }
}

// ===================== K2: merge partials + zero context =====================
__global__ __launch_bounds__(256)
void attn_merge(const float2* __restrict__ part, float2* __restrict__ stats,
                float* __restrict__ Ctx)
{
    const int t = blockIdx.x * 256 + threadIdx.x;
    if (t < NROWS) {
        float mp[KSPLIT], lp[KSPLIT];
        #pragma unroll
        for (int sp = 0; sp < KSPLIT; ++sp) {
            float2 v = part[(size_t)sp * NROWS + t];
            mp[sp] = v.x; lp[sp] = v.y;
        }
        float m = fmaxf(fmaxf(mp[0], mp[1]), fmaxf(mp[2], mp[3]));
        float l = 0.f;
        #pragma unroll
        for (int sp = 0; sp < KSPLIT; ++sp) l += lp[sp] * __expf(mp[sp] - m);
        stats[t] = make_float2(m, 1.0f / l);
    }
    // zero the context region (atomics accumulate into it in K3)
    float4* C4 = (float4*)Ctx;
    const int n4 = BATCH * SDIM * DDIM / 4;
    const int nthr = gridDim.x * 256;
    for (int i = t; i < n4; i += nthr) C4[i] = make_float4(0.f, 0.f, 0.f, 0.f);
}

// ================= K3: emit filter + accumulate context =================
__global__ __launch_bounds__(256, 4)
void attn_emit(const float* __restrict__ Kg, const float* __restrict__ Vg,
               const float* __restrict__ Qg, const int* __restrict__ Mg,
               const float2* __restrict__ stats, float* __restrict__ Ctx,
               float* __restrict__ Filt)
{
    __shared__ short Klds[KBLK][KSTR];
    __shared__ short VTlds[DDIM][KSTR];
    __shared__ short Plds[4][16][KSTR];   // bf16 P tile per wave
    __shared__ int   Mlds[KBLK];

    const int wg = blockIdx.x;
    const int b = wg & 7;
    const int qt = (wg >> 3) & 31;
    const int sp = wg >> 8;
    const int tid = threadIdx.x;
    const int w = tid >> 6, lane = tid & 63, col = lane & 15, quad = lane >> 4;

    const float* Kb = Kg + (size_t)b * SDIM * DDIM;
    const float* Qb = Qg + (size_t)b * SDIM * DDIM;
    const float* Vb = Vg + (size_t)b * SDIM * DDIM;
    const int*   Mb = Mg + (size_t)b * SDIM;
    float* Ctxb  = Ctx  + (size_t)b * SDIM * DDIM;
    float* Filtb = Filt + (size_t)b * SDIM * SDIM;

    bf16x8 aq[2];
    {
        const float* qsrc = Qb + (size_t)(qt * 64 + w * 16 + col) * DDIM + quad * 8;
        #pragma unroll
        for (int c = 0; c < 2; ++c) {
            float4 f0 = *(const float4*)(qsrc + c * 32);
            float4 f1 = *(const float4*)(qsrc + c * 32 + 4);
            bf16x8 a;
            a[0]=f2bf(f0.x); a[1]=f2bf(f0.y); a[2]=f2bf(f0.z); a[3]=f2bf(f0.w);
            a[4]=f2bf(f1.x); a[5]=f2bf(f1.y); a[6]=f2bf(f1.z); a[7]=f2bf(f1.w);
            aq[c] = a;
        }
    }

    // final softmax stats for this lane's 4 rows
    float mrow[4], invl[4];
    #pragma unroll
    for (int r = 0; r < 4; ++r) {
        float2 s2 = stats[b * SDIM + qt * 64 + w * 16 + quad * 4 + r];
        mrow[r] = s2.x; invl[r] = s2.y;
    }

    const int sk_key = tid >> 2;
    const int sk_d0  = (tid & 3) * 16;
    const int sv_d0  = (tid & 15) * 4;
    const int sv_k0  = (tid >> 4) * 4;
    const int kb0 = sp * BPW * KBLK;

    f32x4 Oacc[4];
    #pragma unroll
    for (int dt = 0; dt < 4; ++dt) Oacc[dt] = (f32x4){0.f, 0.f, 0.f, 0.f};

    float4 kreg[4], vreg[4];
    int mreg = 0;
    {
        const float* srck = Kb + (size_t)(kb0 + sk_key) * DDIM + sk_d0;
        #pragma unroll
        for (int i = 0; i < 4; ++i) kreg[i] = *(const float4*)(srck + i * 4);
        const float* srcv = Vb + (size_t)(kb0 + sv_k0) * DDIM + sv_d0;
        #pragma unroll
        for (int i = 0; i < 4; ++i) vreg[i] = *(const float4*)(srcv + (size_t)i * DDIM);
        if (tid < KBLK) mreg = Mb[kb0 + tid];
    }

    for (int kb = 0; kb < BPW; ++kb) {
        const int kbase = kb0 + kb * KBLK;
        __syncthreads();
        {
            bf16x8 p0, p1;
            p0[0]=f2bf(kreg[0].x); p0[1]=f2bf(kreg[0].y); p0[2]=f2bf(kreg[0].z); p0[3]=f2bf(kreg[0].w);
            p0[4]=f2bf(kreg[1].x); p0[5]=f2bf(kreg[1].y); p0[6]=f2bf(kreg[1].z); p0[7]=f2bf(kreg[1].w);
            p1[0]=f2bf(kreg[2].x); p1[1]=f2bf(kreg[2].y); p1[2]=f2bf(kreg[2].z); p1[3]=f2bf(kreg[2].w);
            p1[4]=f2bf(kreg[3].x); p1[5]=f2bf(kreg[3].y); p1[6]=f2bf(kreg[3].z); p1[7]=f2bf(kreg[3].w);
            *(bf16x8*)&Klds[sk_key][sk_d0]     = p0;
            *(bf16x8*)&Klds[sk_key][sk_d0 + 8] = p1;
            #pragma unroll
            for (int dd = 0; dd < 4; ++dd) {
                bf16x4 pv;
                pv[0] = f2bf(fidx(vreg[0], dd));
                pv[1] = f2bf(fidx(vreg[1], dd));
                pv[2] = f2bf(fidx(vreg[2], dd));
                pv[3] = f2bf(fidx(vreg[3], dd));
                *(bf16x4*)&VTlds[sv_d0 + dd][sv_k0] = pv;
            }
            if (tid < KBLK) Mlds[tid] = mreg;
        }
        __syncthreads();
        if (kb + 1 < BPW) {
            const float* srck = Kb + (size_t)(kb0 + (kb + 1) * KBLK + sk_key) * DDIM + sk_d0;
            #pragma unroll
            for (int i = 0; i < 4; ++i) kreg[i] = *(const float4*)(srck + i * 4);
            const float* srcv = Vb + (size_t)(kb0 + (kb + 1) * KBLK + sv_k0) * DDIM + sv_d0;
            #pragma unroll
            for (int i = 0; i < 4; ++i) vreg[i] = *(const float4*)(srcv + (size_t)i * DDIM);
            if (tid < KBLK) mreg = Mb[kb0 + (kb + 1) * KBLK + tid];
        }

        // scores -> p -> (direct global store, bf16 LDS park)
        #pragma unroll
        for (int t = 0; t < 4; ++t) {
            f32x4 acc = {0.f, 0.f, 0.f, 0.f};
            #pragma unroll
            for (int c = 0; c < 2; ++c) {
                bf16x8 bk = *(const bf16x8*)&Klds[t * 16 + col][c * 32 + quad * 8];
                acc = __builtin_amdgcn_mfma_f32_16x16x32_bf16(aq[c], bk, acc, 0, 0, 0);
            }
            const int mk = Mlds[t * 16 + col];
            #pragma unroll
            for (int r = 0; r < 4; ++r) {
                float p = mk ? 0.0f : __expf(acc[r] * SCALE - mrow[r]) * invl[r];
                Filtb[(size_t)(qt * 64 + w * 16 + quad * 4 + r) * SDIM + kbase + t * 16 + col] = p;
                Plds[w][quad * 4 + r][t * 16 + col] = f2bf(p);
            }
        }

        // O += P * V
        #pragma unroll
        for (int c = 0; c < 2; ++c) {
            bf16x8 ap = *(const bf16x8*)&Plds[w][col][c * 32 + quad * 8];
            #pragma unroll
            for (int dt = 0; dt < 4; ++dt) {
                bf16x8 bv = *(const bf16x8*)&VTlds[dt * 16 + col][c * 32 + quad * 8];
                Oacc[dt] = __builtin_amdgcn_mfma_f32_16x16x32_bf16(ap, bv, Oacc[dt], 0, 0, 0);
            }
        }
    }

    // accumulate partial context (4-way contention across key-splits)
    #pragma unroll
    for (int dt = 0; dt < 4; ++dt) {
        #pragma unroll
        for (int r = 0; r < 4; ++r) {
            unsafeAtomicAdd(&Ctxb[(size_t)(qt * 64 + w * 16 + quad * 4 + r) * DDIM + dt * 16 + col],
                            Oacc[dt][r]);
        }
    }
}

extern "C" void kernel_launch(void* const* d_in, const int* in_sizes, int n_in,
                              void* d_out, int out_size, void* d_ws, size_t ws_size,
                              hipStream_t stream) {
    // setup_inputs order: key, query, value, query_attention_mask
    const float* Kg = (const float*)d_in[0];
    const float* Qg = (const float*)d_in[1];
    const float* Vg = (const float*)d_in[2];
    const int*   Mg = (const int*)d_in[3];
    float* Ctx  = (float*)d_out;                                   // [8,2048,64]
    float* Filt = (float*)d_out + (size_t)BATCH * SDIM * DDIM;     // [8,2048,2048]

    float2* part  = (float2*)d_ws;                 // [KSPLIT][NROWS] partial (m,l): 512 KB
    float2* stats = part + (size_t)KSPLIT * NROWS; // [NROWS] (m, 1/l): 128 KB

    // 8 batches x 32 qtiles x 4 key-splits = 1024 WGs (sp = wg>>8 decode)
    attn_stats<<<dim3(BATCH * NBLK * KSPLIT), dim3(256), 0, stream>>>(Kg, Qg, Mg, part);
    attn_merge<<<dim3(256), dim3(256), 0, stream>>>(part, stats, Ctx);
    attn_emit<<<dim3(BATCH * NBLK * KSPLIT), dim3(256), 0, stream>>>(Kg, Vg, Qg, Mg, stats, Ctx, Filt);
}